// Round 4
// baseline (462.167 us; speedup 1.0000x reference)
//
#include <hip/hip_runtime.h>
#include <hip/hip_bf16.h>
#include <stdint.h>

// LinearDiscriminator: [T,B,H] fp32 -> MLP(1024->100->10->1) -> logsigmoid
// -> masked sum over T -> exp -> [B] fp32.  T=2048 B=32 H=1024.
// R4: ALL global accesses lane-contiguous.
//  - W1 pre-packed into MFMA-fragment order in d_ws; staged per BK=64 chunk
//    via global_load_lds (lane-linear 16B, coalesced, conflict-free LDS).
//  - Encoder staged via coalesced 32B/thread loads -> bf16 -> fragment-packed
//    LDS (ds_write_b128), row-predicated on t < len[b].
//  - Double-buffered, 1 barrier/chunk; A-loads for k+1 issue before MFMA of k.

#define H_DIM  1024
#define L1_DIM 100
#define L2_DIM 10
#define NPART  512              // mlp_main grid (M=128 rows/block)

#define W1P_ELEMS (112 * 1024)  // fragment-packed bf16
#define W2P_ELEMS (16 * 128)
#define PART_OFF_BYTES ((W1P_ELEMS + W2P_ELEMS) * 2)

#define W1CH   14336            // one W1 chunk (112x64 bf16), fragment-packed
#define ACH    16384            // one A chunk (128x64 bf16), fragment-packed
#define W1_OFF 0                // [2][14336]
#define A_OFF  28672            // [2][16384]
#define H_OFF  28672            // ldsH [128][136] bf16 aliases A dbuf (34816 B)
#define W2_OFF 63488            // [16][136] bf16 = 4352
#define PRT_OFF 67840           // float[4][32]
#define LDS_TOTAL 68352

typedef float v4f __attribute__((ext_vector_type(4)));
typedef short s8  __attribute__((ext_vector_type(8)));

static __device__ __forceinline__ unsigned short f2bf(float f) {
    unsigned int u = __float_as_uint(f);
    u += 0x7fffu + ((u >> 16) & 1u);
    return (unsigned short)(u >> 16);
}

static __device__ __forceinline__ s8 pack8(float4 a, float4 b) {
    union { s8 v; __hip_bfloat162 h[4]; } u;
    u.h[0] = __float22bfloat162_rn(make_float2(a.x, a.y));
    u.h[1] = __float22bfloat162_rn(make_float2(a.z, a.w));
    u.h[2] = __float22bfloat162_rn(make_float2(b.x, b.y));
    u.h[3] = __float22bfloat162_rn(make_float2(b.z, b.w));
    return u.v;
}

// ---------------- kernel 0: pack W1 into fragment order, pad W2 ----------------
// w1p slot s = kc*896 + (ks*7+nt)*64 + lane (lane = q*16+m):
//   holds W1bf[nt*16+m][kc*64+ks*32+q*8 .. +7]
__global__ void convert_weights(const float* __restrict__ W1,
                                const float* __restrict__ W2,
                                unsigned short* __restrict__ wsb) {
    int s = blockIdx.x * 256 + threadIdx.x;
    union { uint4 u; unsigned short h[8]; } o;
    if (s < 14336) {
        int lane = s & 63, rest = s >> 6;     // rest = kc*14 + ks*7 + nt
        int nt = rest % 7, ksc = rest / 7;    // ksc = kc*2 + ks
        int m = lane & 15, q = lane >> 4;
        int row = nt * 16 + m;
        int col = ksc * 32 + q * 8;
        if (row < L1_DIM) {
            const float* src = W1 + row * H_DIM + col;
#pragma unroll
            for (int e = 0; e < 8; ++e) o.h[e] = f2bf(src[e]);
        } else {
            o.u = make_uint4(0u, 0u, 0u, 0u);
        }
        *(uint4*)(wsb + s * 8) = o.u;
    } else if (s < 14336 + 256) {
        int j = s - 14336;                    // W2 padded [16][128]
        int r = j >> 4, c = (j & 15) * 8;
#pragma unroll
        for (int e = 0; e < 8; ++e) {
            int cc = c + e;
            o.h[e] = (r < L2_DIM && cc < L1_DIM) ? f2bf(W2[r * L1_DIM + cc]) : 0;
        }
        *(uint4*)(wsb + W1P_ELEMS + j * 8) = o.u;
    }
}

// ---------------- kernel 1: main fused MLP ----------------
__global__ __launch_bounds__(256) void mlp_main(
    const float* __restrict__ enc,      // [T][B][H] fp32
    const int*   __restrict__ lenp,     // int32 or int64 (runtime-detected)
    const float* __restrict__ b1,
    const float* __restrict__ b2,
    const float* __restrict__ W3,
    const float* __restrict__ b3,
    const unsigned short* __restrict__ w1p,  // fragment-packed bf16
    const unsigned short* __restrict__ w2p,  // bf16 [16][128]
    float* __restrict__ partials)            // fp32 [32][NPART]
{
    __shared__ __align__(16) unsigned char smem[LDS_TOTAL];

    const int tid  = threadIdx.x;
    const int blk  = blockIdx.x;
    const int lane = tid & 63;
    const int w    = tid >> 6;
    const int m    = lane & 15;
    const int q    = lane >> 4;

    const bool is64 = (lenp[1] == 0);  // lengths>=1: int32 word1 != 0

    int maxlen = 0;
    for (int i = 0; i < 32; ++i) {
        int L = is64 ? lenp[2 * i] : lenp[i];
        maxlen = max(maxlen, L);
    }
    if (4 * blk >= maxlen) {
        if (tid < 32) partials[tid * NPART + blk] = 0.0f;
        return;
    }

    // A-staging mapping: thread -> (row r in 32-row group, 8-col group)
    const int srow = tid >> 3;            // 0..31 == b of this thread's rows
    const int scg  = tid & 7;
    const int sks  = scg >> 2;
    const int sq   = scg & 3;
    const int sf   = srow >> 4;
    const int sm   = srow & 15;
    const int sslot = sq * 16 + sm;       // consumer lane for this slot
    const int slen = is64 ? lenp[2 * srow] : lenp[srow];
    const float* sp = enc + ((size_t)(blk * 128) + srow) * H_DIM + scg * 8;

    // compute-side wave t / predicates
    const int t = 4 * blk + w;            // wave w covers rows w*32..+31 (t fixed)
    const bool waveActive = (t < maxlen);

    // stage W2 -> LDS [16][136]
    {
        int r = tid >> 4, c = (tid & 15) * 8;
        *(uint4*)(smem + W2_OFF + r * 272 + c * 2) = *(const uint4*)(w2p + r * 128 + c);
    }

    // per-lane epilogue constants
    float b1v[7];
#pragma unroll
    for (int nt = 0; nt < 7; ++nt) {
        int n = nt * 16 + m;
        b1v[nt] = (n < L1_DIM) ? b1[n] : 0.0f;
    }
    const float b2v = (m < L2_DIM) ? b2[m] : 0.0f;
    const float w3v = (m < L2_DIM) ? W3[m] : 0.0f;
    const float b3s = b3[0];

    v4f acc0[7], acc1[7];
#pragma unroll
    for (int nt = 0; nt < 7; ++nt) { acc0[nt] = (v4f)0.0f; acc1[nt] = (v4f)0.0f; }

    const float4 z4c = make_float4(0.f, 0.f, 0.f, 0.f);
    float4 pa[8];

// W1 chunk staging: lane-linear 16B global_load_lds (coalesced, conflict-free)
#define STAGEW(kc, BASE)                                                     \
    {                                                                        \
        _Pragma("unroll")                                                    \
        for (int it = 0; it < 4; ++it) {                                     \
            int j = it * 256 + tid;                                          \
            if (it < 3 || tid < 128) {                                       \
                __builtin_amdgcn_global_load_lds(                            \
                    (const __attribute__((address_space(1))) unsigned int*)  \
                        (w1p + (size_t)(kc) * 7168 + j * 8),                 \
                    (__attribute__((address_space(3))) unsigned int*)        \
                        (smem + (BASE) + (j & ~63) * 16),                    \
                    16, 0, 0);                                               \
            }                                                                \
        }                                                                    \
    }

// A loads for chunk kc -> regs (coalesced 32B/thread, row-predicated)
#define LOADA(kc)                                                            \
    {                                                                        \
        _Pragma("unroll")                                                    \
        for (int p = 0; p < 4; ++p) {                                        \
            bool pr = (4 * blk + p) < slen;                                  \
            const float* s_ = sp + p * 32768 + (kc) * 64;                    \
            pa[2 * p]     = pr ? *(const float4*)(s_)     : z4c;             \
            pa[2 * p + 1] = pr ? *(const float4*)(s_ + 4) : z4c;             \
        }                                                                    \
    }

// A regs -> fragment-packed LDS: slot (p*4 + f*2 + ks)*64 + lane, 16B each
#define WRITEA(BASE)                                                         \
    {                                                                        \
        _Pragma("unroll")                                                    \
        for (int p = 0; p < 4; ++p) {                                        \
            s8 v_ = pack8(pa[2 * p], pa[2 * p + 1]);                         \
            *(s8*)(smem + (BASE) + (p * 4 + sf * 2 + sks) * 1024             \
                   + sslot * 16) = v_;                                       \
        }                                                                    \
    }

#define KCOMP(W1RD, ARD)                                                     \
    if (waveActive) {                                                        \
        _Pragma("unroll")                                                    \
        for (int ks = 0; ks < 2; ++ks) {                                     \
            s8 af0 = *(const s8*)(smem + (ARD) + (w * 4 + ks) * 1024         \
                                  + lane * 16);                              \
            s8 af1 = *(const s8*)(smem + (ARD) + (w * 4 + 2 + ks) * 1024     \
                                  + lane * 16);                              \
            _Pragma("unroll")                                                \
            for (int nt = 0; nt < 7; ++nt) {                                 \
                s8 bf = *(const s8*)(smem + (W1RD)                           \
                                     + ((ks * 7 + nt) * 64 + lane) * 16);    \
                acc0[nt] = __builtin_amdgcn_mfma_f32_16x16x32_bf16(          \
                    af0, bf, acc0[nt], 0, 0, 0);                             \
                acc1[nt] = __builtin_amdgcn_mfma_f32_16x16x32_bf16(          \
                    af1, bf, acc1[nt], 0, 0, 0);                             \
            }                                                                \
        }                                                                    \
    }

#define KBODY(kc, W1RD, W1WR, ARD, AWR)                                      \
    {                                                                        \
        if ((kc) < 15) { STAGEW((kc) + 1, W1WR); LOADA((kc) + 1); }          \
        KCOMP(W1RD, ARD);                                                    \
        if ((kc) < 15) { WRITEA(AWR); }                                      \
        __syncthreads();                                                     \
    }

    // prologue: chunk 0 into buffer 0
    STAGEW(0, W1_OFF)
    LOADA(0)
    WRITEA(A_OFF)
    __syncthreads();

    KBODY(0,  W1_OFF,        W1_OFF + W1CH, A_OFF,       A_OFF + ACH)
    KBODY(1,  W1_OFF + W1CH, W1_OFF,        A_OFF + ACH, A_OFF)
    KBODY(2,  W1_OFF,        W1_OFF + W1CH, A_OFF,       A_OFF + ACH)
    KBODY(3,  W1_OFF + W1CH, W1_OFF,        A_OFF + ACH, A_OFF)
    KBODY(4,  W1_OFF,        W1_OFF + W1CH, A_OFF,       A_OFF + ACH)
    KBODY(5,  W1_OFF + W1CH, W1_OFF,        A_OFF + ACH, A_OFF)
    KBODY(6,  W1_OFF,        W1_OFF + W1CH, A_OFF,       A_OFF + ACH)
    KBODY(7,  W1_OFF + W1CH, W1_OFF,        A_OFF + ACH, A_OFF)
    KBODY(8,  W1_OFF,        W1_OFF + W1CH, A_OFF,       A_OFF + ACH)
    KBODY(9,  W1_OFF + W1CH, W1_OFF,        A_OFF + ACH, A_OFF)
    KBODY(10, W1_OFF,        W1_OFF + W1CH, A_OFF,       A_OFF + ACH)
    KBODY(11, W1_OFF + W1CH, W1_OFF,        A_OFF + ACH, A_OFF)
    KBODY(12, W1_OFF,        W1_OFF + W1CH, A_OFF,       A_OFF + ACH)
    KBODY(13, W1_OFF + W1CH, W1_OFF,        A_OFF + ACH, A_OFF)
    KBODY(14, W1_OFF,        W1_OFF + W1CH, A_OFF,       A_OFF + ACH)
    KBODY(15, W1_OFF + W1CH, W1_OFF,        A_OFF + ACH, A_OFF)

#undef KBODY
#undef KCOMP
#undef WRITEA
#undef LOADA
#undef STAGEW

    // ---- h1 = relu(acc + b1) -> ldsH [128][136] bf16 (wave-local rows) ----
    unsigned short* ldsH = (unsigned short*)(smem + H_OFF);
#pragma unroll
    for (int f = 0; f < 2; ++f) {
#pragma unroll
        for (int nt = 0; nt < 7; ++nt) {
#pragma unroll
            for (int reg = 0; reg < 4; ++reg) {
                int row = w * 32 + f * 16 + q * 4 + reg;
                int col = nt * 16 + m;
                float a = f ? acc1[nt][reg] : acc0[nt][reg];
                ldsH[row * 136 + col] = f2bf(fmaxf(a + b1v[nt], 0.0f));
            }
        }
    }
    // zero K-pad cols 112..127 (wave-local rows)
    {
        int row = w * 32 + (lane >> 1);
        int c = 112 + (lane & 1) * 8;
        uint4 z; z.x = z.y = z.z = z.w = 0u;
        *(uint4*)(ldsH + row * 136 + c) = z;
    }
    // wave-local producer/consumer: compiler's lgkmcnt ordering suffices

    // ---- layer-2 MFMA: M=32/wave over K=128 ----
    unsigned short* ldsW2 = (unsigned short*)(smem + W2_OFF);
    v4f acc2[2];
    acc2[0] = (v4f)0.0f; acc2[1] = (v4f)0.0f;
#pragma unroll
    for (int ks2 = 0; ks2 < 4; ++ks2) {
        s8 bw = *(const s8*)(ldsW2 + m * 136 + ks2 * 32 + q * 8);
#pragma unroll
        for (int f = 0; f < 2; ++f) {
            s8 ah = *(const s8*)(ldsH + (w * 32 + f * 16 + m) * 136 + ks2 * 32 + q * 8);
            acc2[f] = __builtin_amdgcn_mfma_f32_16x16x32_bf16(ah, bw, acc2[f], 0, 0, 0);
        }
    }

    // ---- layer 3 + logsigmoid + per-t mask ----
    float* ldsPart = (float*)(smem + PRT_OFF);   // [4][32]
#pragma unroll
    for (int f = 0; f < 2; ++f) {
        v4f zv;
#pragma unroll
        for (int reg = 0; reg < 4; ++reg)
            zv[reg] = fmaxf(acc2[f][reg] + b2v, 0.0f) * w3v;
#pragma unroll
        for (int msk = 1; msk < 16; msk <<= 1) {
#pragma unroll
            for (int reg = 0; reg < 4; ++reg)
                zv[reg] += __shfl_xor(zv[reg], msk, 16);
        }
        if (m == 0) {
#pragma unroll
            for (int reg = 0; reg < 4; ++reg) {
                int b = f * 16 + q * 4 + reg;
                int lenB = is64 ? lenp[2 * b] : lenp[b];
                float logit = zv[reg] + b3s;
                float logp  = fminf(logit, 0.0f) - log1pf(__expf(-fabsf(logit)));
                ldsPart[w * 32 + b] = (t < lenB) ? logp : 0.0f;
            }
        }
    }
    __syncthreads();
    if (tid < 32)
        partials[tid * NPART + blk] =
            (ldsPart[tid] + ldsPart[32 + tid]) + (ldsPart[64 + tid] + ldsPart[96 + tid]);
}

// ---------------- kernel 2: reduce + exp ----------------
__global__ void finalize(const float* __restrict__ partials,
                         float* __restrict__ out) {
    const int b = blockIdx.x;
    const int tid = threadIdx.x;
    float s = 0.0f;
    for (int i = tid; i < NPART; i += 256) s += partials[b * NPART + i];
#pragma unroll
    for (int off = 32; off > 0; off >>= 1) s += __shfl_down(s, off, 64);
    __shared__ float red[4];
    if ((tid & 63) == 0) red[tid >> 6] = s;
    __syncthreads();
    if (tid == 0) out[b] = expf(red[0] + red[1] + red[2] + red[3]);
}

extern "C" void kernel_launch(void* const* d_in, const int* in_sizes, int n_in,
                              void* d_out, int out_size, void* d_ws, size_t ws_size,
                              hipStream_t stream) {
    const float* enc = (const float*)d_in[0];
    const int*   len = (const int*)d_in[1];
    const float* W1  = (const float*)d_in[2];
    const float* b1  = (const float*)d_in[3];
    const float* W2  = (const float*)d_in[4];
    const float* b2  = (const float*)d_in[5];
    const float* W3  = (const float*)d_in[6];
    const float* b3  = (const float*)d_in[7];

    unsigned short* wsb = (unsigned short*)d_ws;
    float* partials = (float*)((char*)d_ws + PART_OFF_BYTES);
    float* out = (float*)d_out;

    convert_weights<<<57, 256, 0, stream>>>(W1, W2, wsb);
    mlp_main<<<NPART, 256, 0, stream>>>(enc, len, b1, b2, W3, b3,
                                        wsb, wsb + W1P_ELEMS, partials);
    finalize<<<32, 256, 0, stream>>>(partials, out);
}